// Round 8
// baseline (232.949 us; speedup 1.0000x reference)
//
#include <hip/hip_runtime.h>

#define NCOMP   100000
#define D_CA    12
#define D_COURT 4
#define D_CATE  4
#define D_TOT   20
#define NCAUSE  200
#define NCOURT  50
#define NRES    10
#define CHUNK   8
#define TPB     256
#define BLK_EV  (TPB * CHUNK)   // 2048 events per block
#define MAXSLOT 112             // company slots per block (span ~49 expected)

__device__ __forceinline__ void flush_run(const float (&acc)[D_TOT], int c, int c_first,
                                          float* __restrict__ lds_slot,
                                          const float* __restrict__ lds_w,
                                          float* __restrict__ out) {
    const int slot = c - c_first;
    if (slot < MAXSLOT) {
#pragma unroll
        for (int d = 0; d < D_TOT; ++d)
            atomicAdd(&lds_slot[slot * D_TOT + d], acc[d]);
    } else {
#pragma unroll 1
        for (int o = 0; o < D_TOT; ++o) {
            float s = 0.0f;
#pragma unroll 1
            for (int d = 0; d < D_TOT; ++d) s += acc[d] * lds_w[o * D_TOT + d];
            atomicAdd(&out[c * D_TOT + o], s);
        }
    }
}

// cold path (~1.1% of threads): scalar walk with per-run LDS flushes
__device__ __noinline__ void slow_chunk(long base, int jmax, float dw,
                                        const int* __restrict__ cause_idx,
                                        const int* __restrict__ court_idx,
                                        const int* __restrict__ cate_idx,
                                        const int* __restrict__ seg_ids,
                                        const float* __restrict__ time_interval,
                                        const float* lds_ca, const float* lds_court,
                                        const float* lds_cate, const float* lds_w,
                                        float* lds_slot, int c_first,
                                        float* __restrict__ out) {
    float acc[D_TOT];
#pragma unroll
    for (int d = 0; d < D_TOT; ++d) acc[d] = 0.0f;
    int cur = seg_ids[base];
#pragma unroll 1
    for (int j = 0; j < jmax; ++j) {
        const int sj = seg_ids[base + j];
        if (sj != cur) {
            flush_run(acc, cur, c_first, lds_slot, lds_w, out);
#pragma unroll
            for (int d = 0; d < D_TOT; ++d) acc[d] = 0.0f;
            cur = sj;
        }
        const int ca = cause_idx[base + j];
        const int co = court_idx[base + j];
        const int ct = cate_idx[base + j];
        const float t = time_interval[base + j];
        const float dec = __fdividef(dw, __logf(2.718281828459045f + t));
#pragma unroll 1
        for (int d = 0; d < D_CA; ++d) acc[d] += dec * lds_ca[ca * D_CA + d];
#pragma unroll 1
        for (int d = 0; d < D_COURT; ++d) acc[D_CA + d] += dec * lds_court[co * D_COURT + d];
#pragma unroll 1
        for (int d = 0; d < D_CATE; ++d) acc[D_CA + D_COURT + d] += dec * lds_cate[ct * D_CATE + d];
    }
    flush_run(acc, cur, c_first, lds_slot, lds_w, out);
}

__global__ __launch_bounds__(TPB, 4)   // VGPR cap 128: keep ≥4 waves/SIMD
void block_seg_kernel(const int* __restrict__ cause_idx,
                      const int* __restrict__ court_idx,
                      const int* __restrict__ cate_idx,
                      const int* __restrict__ seg_ids,
                      const float* __restrict__ time_interval,
                      const float* __restrict__ ca_table,
                      const float* __restrict__ court_table,
                      const float* __restrict__ cate_table,
                      const float* __restrict__ proj_w,
                      const float* __restrict__ decay_w,
                      int n_events,
                      float* __restrict__ out) {
    __shared__ __align__(16) float lds_ca[NCAUSE * D_CA];
    __shared__ __align__(16) float lds_court[NCOURT * D_COURT];
    __shared__ __align__(16) float lds_cate[NRES * D_CATE];
    __shared__ __align__(16) float lds_w[D_TOT * D_TOT];
    __shared__ __align__(16) float lds_slot[MAXSLOT * D_TOT];
    __shared__ int sh_c0, sh_c1;

    for (int i = threadIdx.x; i < NCAUSE * D_CA; i += TPB) lds_ca[i] = ca_table[i];
    for (int i = threadIdx.x; i < NCOURT * D_COURT; i += TPB) lds_court[i] = court_table[i];
    for (int i = threadIdx.x; i < NRES * D_CATE; i += TPB) lds_cate[i] = cate_table[i];
    for (int i = threadIdx.x; i < D_TOT * D_TOT; i += TPB) lds_w[i] = proj_w[i];
    for (int i = threadIdx.x; i < MAXSLOT * D_TOT; i += TPB) lds_slot[i] = 0.0f;
    if (threadIdx.x == 0) {
        const long b0 = (long)blockIdx.x * BLK_EV;
        long b1 = b0 + BLK_EV;
        if (b1 > n_events) b1 = n_events;
        sh_c0 = seg_ids[b0];
        sh_c1 = seg_ids[b1 - 1];
    }
    __syncthreads();

    const float dw = decay_w[0];
    const int c_first = sh_c0;
    const long base = (long)blockIdx.x * BLK_EV + (long)threadIdx.x * CHUNK;

    if (base < n_events) {
        if (base + CHUNK > n_events) {
            slow_chunk(base, (int)(n_events - base), dw, cause_idx, court_idx, cate_idx,
                       seg_ids, time_interval, lds_ca, lds_court, lds_cate, lds_w,
                       lds_slot, c_first, out);
        } else {
            // ---- ALL 10 vector loads issued up front: one touch per line, 10-deep MLP
            const int4   sa = ((const int4*)(seg_ids + base))[0];
            const int4   sb = ((const int4*)(seg_ids + base))[1];
            const int4   ca_a = ((const int4*)(cause_idx + base))[0];
            const int4   ca_b = ((const int4*)(cause_idx + base))[1];
            const int4   co_a = ((const int4*)(court_idx + base))[0];
            const int4   co_b = ((const int4*)(court_idx + base))[1];
            const int4   ct_a = ((const int4*)(cate_idx + base))[0];
            const int4   ct_b = ((const int4*)(cate_idx + base))[1];
            const float4 tm_a = ((const float4*)(time_interval + base))[0];
            const float4 tm_b = ((const float4*)(time_interval + base))[1];

            const int first = sa.x, last = sb.w;
            const bool slow =
                ((sa.y != first) & (sa.y != last)) | ((sa.z != first) & (sa.z != last)) |
                ((sa.w != first) & (sa.w != last)) | ((sb.x != first) & (sb.x != last)) |
                ((sb.y != first) & (sb.y != last)) | ((sb.z != first) & (sb.z != last));
            // fast chunk == two sorted runs: seg[e]==first iff e<k
            const int k =
                (sa.x == first) + (sa.y == first) + (sa.z == first) + (sa.w == first) +
                (sb.x == first) + (sb.y == first) + (sb.z == first) + (sb.w == first);

            if (slow) {
                slow_chunk(base, CHUNK, dw, cause_idx, court_idx, cate_idx,
                           seg_ids, time_interval, lds_ca, lds_court, lds_cate, lds_w,
                           lds_slot, c_first, out);
            } else {
                float accH[D_TOT], accT[D_TOT];
#pragma unroll
                for (int d = 0; d < D_TOT; ++d) { accH[d] = 0.0f; accT[d] = 0.0f; }

#define PROC(CA, CO, CT, T, E)                                                \
    do {                                                                      \
        const float dec  = __fdividef(dw, __logf(2.718281828459045f + (T)));  \
        const float decT = ((E) >= k) ? dec : 0.0f;                           \
        const float decH = dec - decT;                                        \
        const float4* car = (const float4*)(lds_ca + (CA) * D_CA);            \
        const float4 a0 = car[0], a1 = car[1], a2 = car[2];                   \
        const float4 b0 = *(const float4*)(lds_court + (CO) * D_COURT);       \
        const float4 c0 = *(const float4*)(lds_cate + (CT) * D_CATE);         \
        accH[0]  += decH * a0.x;  accT[0]  += decT * a0.x;                    \
        accH[1]  += decH * a0.y;  accT[1]  += decT * a0.y;                    \
        accH[2]  += decH * a0.z;  accT[2]  += decT * a0.z;                    \
        accH[3]  += decH * a0.w;  accT[3]  += decT * a0.w;                    \
        accH[4]  += decH * a1.x;  accT[4]  += decT * a1.x;                    \
        accH[5]  += decH * a1.y;  accT[5]  += decT * a1.y;                    \
        accH[6]  += decH * a1.z;  accT[6]  += decT * a1.z;                    \
        accH[7]  += decH * a1.w;  accT[7]  += decT * a1.w;                    \
        accH[8]  += decH * a2.x;  accT[8]  += decT * a2.x;                    \
        accH[9]  += decH * a2.y;  accT[9]  += decT * a2.y;                    \
        accH[10] += decH * a2.z;  accT[10] += decT * a2.z;                    \
        accH[11] += decH * a2.w;  accT[11] += decT * a2.w;                    \
        accH[12] += decH * b0.x;  accT[12] += decT * b0.x;                    \
        accH[13] += decH * b0.y;  accT[13] += decT * b0.y;                    \
        accH[14] += decH * b0.z;  accT[14] += decT * b0.z;                    \
        accH[15] += decH * b0.w;  accT[15] += decT * b0.w;                    \
        accH[16] += decH * c0.x;  accT[16] += decT * c0.x;                    \
        accH[17] += decH * c0.y;  accT[17] += decT * c0.y;                    \
        accH[18] += decH * c0.z;  accT[18] += decT * c0.z;                    \
        accH[19] += decH * c0.w;  accT[19] += decT * c0.w;                    \
    } while (0)

                PROC(ca_a.x, co_a.x, ct_a.x, tm_a.x, 0);
                PROC(ca_a.y, co_a.y, ct_a.y, tm_a.y, 1);
                PROC(ca_a.z, co_a.z, ct_a.z, tm_a.z, 2);
                PROC(ca_a.w, co_a.w, ct_a.w, tm_a.w, 3);
                PROC(ca_b.x, co_b.x, ct_b.x, tm_b.x, 4);
                PROC(ca_b.y, co_b.y, ct_b.y, tm_b.y, 5);
                PROC(ca_b.z, co_b.z, ct_b.z, tm_b.z, 6);
                PROC(ca_b.w, co_b.w, ct_b.w, tm_b.w, 7);
#undef PROC

                flush_run(accH, first, c_first, lds_slot, lds_w, out);
                if (last != first)
                    flush_run(accT, last, c_first, lds_slot, lds_w, out);
            }
        }
    }

    __syncthreads();

    // epilogue: project each slot once; plain store for interior companies,
    // atomicAdd only for the block's 2 boundary companies
    const int nslots = sh_c1 - c_first + 1;
    const int capped = nslots < MAXSLOT ? nslots : MAXSLOT;
    for (int i = threadIdx.x; i < capped * D_TOT; i += TPB) {
        const int slot = i / D_TOT;
        const int o = i - slot * D_TOT;
        float s = 0.0f;
#pragma unroll
        for (int d = 0; d < D_TOT; ++d) s += lds_slot[slot * D_TOT + d] * lds_w[o * D_TOT + d];
        const int c = c_first + slot;
        if (slot == 0 || slot == nslots - 1) atomicAdd(&out[c * D_TOT + o], s);
        else out[c * D_TOT + o] = s;
    }
}

extern "C" void kernel_launch(void* const* d_in, const int* in_sizes, int n_in,
                              void* d_out, int out_size, void* d_ws, size_t ws_size,
                              hipStream_t stream) {
    const int* cause_idx = (const int*)d_in[0];
    const int* court_idx = (const int*)d_in[1];
    const int* cate_idx  = (const int*)d_in[2];
    const int* seg_ids   = (const int*)d_in[3];
    const float* time_interval = (const float*)d_in[4];
    const float* ca_table      = (const float*)d_in[5];
    const float* court_table   = (const float*)d_in[6];
    const float* cate_table    = (const float*)d_in[7];
    const float* proj_w        = (const float*)d_in[8];
    const float* decay_w       = (const float*)d_in[9];
    float* out = (float*)d_out;
    const int n_events = in_sizes[0];

    // boundary-company atomics + empty-company gaps need zeroed output
    hipMemsetAsync(out, 0, (size_t)out_size * sizeof(float), stream);

    const int blocks = (n_events + BLK_EV - 1) / BLK_EV;  // 2048
    block_seg_kernel<<<blocks, TPB, 0, stream>>>(
        cause_idx, court_idx, cate_idx, seg_ids, time_interval,
        ca_table, court_table, cate_table, proj_w, decay_w,
        n_events, out);
}

// Round 9
// 210.642 us; speedup vs baseline: 1.1059x; 1.1059x over previous
//
#include <hip/hip_runtime.h>

#define NCOMP   100000
#define D_CA    12
#define D_COURT 4
#define D_CATE  4
#define D_TOT   20
#define NCAUSE  200
#define NCOURT  50
#define NRES    10
#define CHUNK   8
#define TPB     256
#define BLK_EV  (TPB * CHUNK)   // 2048 events per block
#define MAXSLOT 112             // company slots per block (span ~49 expected)

__device__ __forceinline__ void flush_run(const float (&acc)[D_TOT], int c, int c_first,
                                          float* __restrict__ lds_slot,
                                          const float* __restrict__ lds_w,
                                          float* __restrict__ out) {
    const int slot = c - c_first;
    if (slot < MAXSLOT) {
#pragma unroll
        for (int d = 0; d < D_TOT; ++d)
            atomicAdd(&lds_slot[slot * D_TOT + d], acc[d]);
    } else {
#pragma unroll 1
        for (int o = 0; o < D_TOT; ++o) {
            float s = 0.0f;
#pragma unroll 1
            for (int d = 0; d < D_TOT; ++d) s += acc[d] * lds_w[o * D_TOT + d];
            atomicAdd(&out[c * D_TOT + o], s);
        }
    }
}

// cold path (~1.6% of threads): scalar walk with per-run LDS flushes
__device__ __noinline__ void slow_chunk(long base, int jmax, float dw,
                                        const int* __restrict__ cause_idx,
                                        const int* __restrict__ court_idx,
                                        const int* __restrict__ cate_idx,
                                        const int* __restrict__ seg_ids,
                                        const float* __restrict__ time_interval,
                                        const float* lds_ca, const float* lds_court,
                                        const float* lds_cate, const float* lds_w,
                                        float* lds_slot, int c_first,
                                        float* __restrict__ out) {
    float acc[D_TOT];
#pragma unroll
    for (int d = 0; d < D_TOT; ++d) acc[d] = 0.0f;
    int cur = seg_ids[base];
#pragma unroll 1
    for (int j = 0; j < jmax; ++j) {
        const int sj = seg_ids[base + j];
        if (sj != cur) {
            flush_run(acc, cur, c_first, lds_slot, lds_w, out);
#pragma unroll
            for (int d = 0; d < D_TOT; ++d) acc[d] = 0.0f;
            cur = sj;
        }
        const int ca = cause_idx[base + j];
        const int co = court_idx[base + j];
        const int ct = cate_idx[base + j];
        const float t = time_interval[base + j];
        const float dec = __fdividef(dw, __logf(2.718281828459045f + t));
#pragma unroll 1
        for (int d = 0; d < D_CA; ++d) acc[d] += dec * lds_ca[ca * D_CA + d];
#pragma unroll 1
        for (int d = 0; d < D_COURT; ++d) acc[D_CA + d] += dec * lds_court[co * D_COURT + d];
#pragma unroll 1
        for (int d = 0; d < D_CATE; ++d) acc[D_CA + D_COURT + d] += dec * lds_cate[ct * D_CATE + d];
    }
    flush_run(acc, cur, c_first, lds_slot, lds_w, out);
}

// NOTE: no min-waves in launch_bounds — R8 showed hipcc spills to scratch
// (184 MB HBM writes) to honor the cap. Let the allocator take ~110-130 VGPR.
__global__ __launch_bounds__(TPB)
void block_seg_kernel(const int* __restrict__ cause_idx,
                      const int* __restrict__ court_idx,
                      const int* __restrict__ cate_idx,
                      const int* __restrict__ seg_ids,
                      const float* __restrict__ time_interval,
                      const float* __restrict__ ca_table,
                      const float* __restrict__ court_table,
                      const float* __restrict__ cate_table,
                      const float* __restrict__ proj_w,
                      const float* __restrict__ decay_w,
                      int n_events,
                      float* __restrict__ out) {
    __shared__ __align__(16) float lds_ca[NCAUSE * D_CA];
    __shared__ __align__(16) float lds_court[NCOURT * D_COURT];
    __shared__ __align__(16) float lds_cate[NRES * D_CATE];
    __shared__ __align__(16) float lds_w[D_TOT * D_TOT];
    __shared__ __align__(16) float lds_slot[MAXSLOT * D_TOT];
    __shared__ int sh_c0, sh_c1;

    for (int i = threadIdx.x; i < NCAUSE * D_CA; i += TPB) lds_ca[i] = ca_table[i];
    for (int i = threadIdx.x; i < NCOURT * D_COURT; i += TPB) lds_court[i] = court_table[i];
    for (int i = threadIdx.x; i < NRES * D_CATE; i += TPB) lds_cate[i] = cate_table[i];
    for (int i = threadIdx.x; i < D_TOT * D_TOT; i += TPB) lds_w[i] = proj_w[i];
    for (int i = threadIdx.x; i < MAXSLOT * D_TOT; i += TPB) lds_slot[i] = 0.0f;
    if (threadIdx.x == 0) {
        const long b0 = (long)blockIdx.x * BLK_EV;
        long b1 = b0 + BLK_EV;
        if (b1 > n_events) b1 = n_events;
        sh_c0 = seg_ids[b0];
        sh_c1 = seg_ids[b1 - 1];
    }
    __syncthreads();

    const float dw = decay_w[0];
    const int c_first = sh_c0;
    const long base = (long)blockIdx.x * BLK_EV + (long)threadIdx.x * CHUNK;

    if (base < n_events) {
        if (base + CHUNK > n_events) {
            slow_chunk(base, (int)(n_events - base), dw, cause_idx, court_idx, cate_idx,
                       seg_ids, time_interval, lds_ca, lds_court, lds_cate, lds_w,
                       lds_slot, c_first, out);
        } else {
            // pass 1: seg analysis in a dead scope (2 vectors die before hot loop)
            int first, last, k;
            bool slow;
            {
                const int4 sa = ((const int4*)(seg_ids + base))[0];
                const int4 sb = ((const int4*)(seg_ids + base))[1];
                first = sa.x;
                last  = sb.w;
                slow =
                    ((sa.y != first) & (sa.y != last)) | ((sa.z != first) & (sa.z != last)) |
                    ((sa.w != first) & (sa.w != last)) | ((sb.x != first) & (sb.x != last)) |
                    ((sb.y != first) & (sb.y != last)) | ((sb.z != first) & (sb.z != last));
                // fast chunk == two sorted runs: seg[e]==first iff e<k
                k = (sa.x == first) + (sa.y == first) + (sa.z == first) + (sa.w == first) +
                    (sb.x == first) + (sb.y == first) + (sb.z == first) + (sb.w == first);
            }

            // hoist the 8 stream vectors up front: one touch per line, 8-deep MLP
            const int4   ca_a = ((const int4*)(cause_idx + base))[0];
            const int4   ca_b = ((const int4*)(cause_idx + base))[1];
            const int4   co_a = ((const int4*)(court_idx + base))[0];
            const int4   co_b = ((const int4*)(court_idx + base))[1];
            const int4   ct_a = ((const int4*)(cate_idx + base))[0];
            const int4   ct_b = ((const int4*)(cate_idx + base))[1];
            const float4 tm_a = ((const float4*)(time_interval + base))[0];
            const float4 tm_b = ((const float4*)(time_interval + base))[1];

            if (slow) {
                slow_chunk(base, CHUNK, dw, cause_idx, court_idx, cate_idx,
                           seg_ids, time_interval, lds_ca, lds_court, lds_cate, lds_w,
                           lds_slot, c_first, out);
            } else {
                float accH[D_TOT], accT[D_TOT];
#pragma unroll
                for (int d = 0; d < D_TOT; ++d) { accH[d] = 0.0f; accT[d] = 0.0f; }

#define PROC(CA, CO, CT, T, E)                                                \
    do {                                                                      \
        const float dec  = __fdividef(dw, __logf(2.718281828459045f + (T)));  \
        const float decT = ((E) >= k) ? dec : 0.0f;                           \
        const float decH = dec - decT;                                        \
        const float4* car = (const float4*)(lds_ca + (CA) * D_CA);            \
        const float4 a0 = car[0], a1 = car[1], a2 = car[2];                   \
        const float4 b0 = *(const float4*)(lds_court + (CO) * D_COURT);       \
        const float4 c0 = *(const float4*)(lds_cate + (CT) * D_CATE);         \
        accH[0]  += decH * a0.x;  accT[0]  += decT * a0.x;                    \
        accH[1]  += decH * a0.y;  accT[1]  += decT * a0.y;                    \
        accH[2]  += decH * a0.z;  accT[2]  += decT * a0.z;                    \
        accH[3]  += decH * a0.w;  accT[3]  += decT * a0.w;                    \
        accH[4]  += decH * a1.x;  accT[4]  += decT * a1.x;                    \
        accH[5]  += decH * a1.y;  accT[5]  += decT * a1.y;                    \
        accH[6]  += decH * a1.z;  accT[6]  += decT * a1.z;                    \
        accH[7]  += decH * a1.w;  accT[7]  += decT * a1.w;                    \
        accH[8]  += decH * a2.x;  accT[8]  += decT * a2.x;                    \
        accH[9]  += decH * a2.y;  accT[9]  += decT * a2.y;                    \
        accH[10] += decH * a2.z;  accT[10] += decT * a2.z;                    \
        accH[11] += decH * a2.w;  accT[11] += decT * a2.w;                    \
        accH[12] += decH * b0.x;  accT[12] += decT * b0.x;                    \
        accH[13] += decH * b0.y;  accT[13] += decT * b0.y;                    \
        accH[14] += decH * b0.z;  accT[14] += decT * b0.z;                    \
        accH[15] += decH * b0.w;  accT[15] += decT * b0.w;                    \
        accH[16] += decH * c0.x;  accT[16] += decT * c0.x;                    \
        accH[17] += decH * c0.y;  accT[17] += decT * c0.y;                    \
        accH[18] += decH * c0.z;  accT[18] += decT * c0.z;                    \
        accH[19] += decH * c0.w;  accT[19] += decT * c0.w;                    \
    } while (0)

                PROC(ca_a.x, co_a.x, ct_a.x, tm_a.x, 0);
                PROC(ca_a.y, co_a.y, ct_a.y, tm_a.y, 1);
                PROC(ca_a.z, co_a.z, ct_a.z, tm_a.z, 2);
                PROC(ca_a.w, co_a.w, ct_a.w, tm_a.w, 3);
                PROC(ca_b.x, co_b.x, ct_b.x, tm_b.x, 4);
                PROC(ca_b.y, co_b.y, ct_b.y, tm_b.y, 5);
                PROC(ca_b.z, co_b.z, ct_b.z, tm_b.z, 6);
                PROC(ca_b.w, co_b.w, ct_b.w, tm_b.w, 7);
#undef PROC

                flush_run(accH, first, c_first, lds_slot, lds_w, out);
                if (last != first)
                    flush_run(accT, last, c_first, lds_slot, lds_w, out);
            }
        }
    }

    __syncthreads();

    // epilogue: project each slot once; plain store for interior companies,
    // atomicAdd only for the block's 2 boundary companies
    const int nslots = sh_c1 - c_first + 1;
    const int capped = nslots < MAXSLOT ? nslots : MAXSLOT;
    for (int i = threadIdx.x; i < capped * D_TOT; i += TPB) {
        const int slot = i / D_TOT;
        const int o = i - slot * D_TOT;
        float s = 0.0f;
#pragma unroll
        for (int d = 0; d < D_TOT; ++d) s += lds_slot[slot * D_TOT + d] * lds_w[o * D_TOT + d];
        const int c = c_first + slot;
        if (slot == 0 || slot == nslots - 1) atomicAdd(&out[c * D_TOT + o], s);
        else out[c * D_TOT + o] = s;
    }
}

extern "C" void kernel_launch(void* const* d_in, const int* in_sizes, int n_in,
                              void* d_out, int out_size, void* d_ws, size_t ws_size,
                              hipStream_t stream) {
    const int* cause_idx = (const int*)d_in[0];
    const int* court_idx = (const int*)d_in[1];
    const int* cate_idx  = (const int*)d_in[2];
    const int* seg_ids   = (const int*)d_in[3];
    const float* time_interval = (const float*)d_in[4];
    const float* ca_table      = (const float*)d_in[5];
    const float* court_table   = (const float*)d_in[6];
    const float* cate_table    = (const float*)d_in[7];
    const float* proj_w        = (const float*)d_in[8];
    const float* decay_w       = (const float*)d_in[9];
    float* out = (float*)d_out;
    const int n_events = in_sizes[0];

    // boundary-company atomics + empty-company gaps need zeroed output
    hipMemsetAsync(out, 0, (size_t)out_size * sizeof(float), stream);

    const int blocks = (n_events + BLK_EV - 1) / BLK_EV;  // 2048
    block_seg_kernel<<<blocks, TPB, 0, stream>>>(
        cause_idx, court_idx, cate_idx, seg_ids, time_interval,
        ca_table, court_table, cate_table, proj_w, decay_w,
        n_events, out);
}